// Round 2
// baseline (105.686 us; speedup 1.0000x reference)
//
#include <hip/hip_runtime.h>
#include <math.h>

// Chamfer distance via MFMA, pred/gt (4,8192,3) fp32 -> scalar.
// d(q,g) = s_q + s_g - 2 q.g as one K=16 fp16 MFMA dot (2-way fp16 split per
// coord; products exact in fp32 accum):
//   q row:  {xh,xh,xl,xl,yh,yh,yl,yl | zh,zh,zl,zl, 1, 1, sh,sl}
//   t row:  {Xh,Xl,Xh,Xl,Yh,Yl,Yh,Yl | Zh,Zl,Zh,Zl,sh,sl, 1, 1}   (X=-2x etc)
// A = 32 targets, B = 32 queries, v_mfma_f32_32x32x16_f16 (layout verified R5/R6).
// R9: kill the device-scope atomicMin path (262144 RMWs) -- the R7/R8-invariant
// ~35us remainder. Each block now owns 256 queries END-TO-END: loops all 16
// target chunks (LDS double-buffered via reg-prefetch), completes the min
// in-block, stores ONE partial sum (plain store). 256 blocks = 1/CU. A tiny
// 1-block kernel reduces 256 partials -> out. No minbits, no poison
// dependence, no out-init ordering. LDS A-frag-linear: conflict-free reads.

typedef _Float16 half8 __attribute__((ext_vector_type(8)));
typedef float f32x16 __attribute__((ext_vector_type(16)));

#define NPTS   8192
#define TT     512                // targets per LDS chunk (16 KB)
#define NCH    16                 // chunks per cloud

__device__ __forceinline__ void split2(float v, _Float16& h, _Float16& l) {
  h = (_Float16)v; l = (_Float16)(v - (float)h);
}

__device__ __forceinline__ float min_fold(float m, const f32x16& d) {
  // 8 x v_min3_f32 tree over 16 values + carry-in
  float t0 = fminf(fminf(d[0], d[1]), d[2]);
  float t1 = fminf(fminf(d[3], d[4]), d[5]);
  float t2 = fminf(fminf(d[6], d[7]), d[8]);
  float t3 = fminf(fminf(d[9], d[10]), d[11]);
  float t4 = fminf(fminf(d[12], d[13]), d[14]);
  float t5 = fminf(fminf(t0, t1), d[15]);
  float t6 = fminf(fminf(t2, t3), t4);
  return fminf(m, fminf(t5, t6));
}

__device__ __forceinline__ void pack_target(float x, float y, float z,
                                            half8& fa, half8& fb) {
  float s = x * x + y * y + z * z;
  _Float16 xh, xl, yh, yl, zh, zl, sh, sl;
  split2(x, xh, xl); split2(y, yh, yl); split2(z, zh, zl); split2(s, sh, sl);
  _Float16 one = (_Float16)1.0f;
  _Float16 Xh = (_Float16)(-2.f * (float)xh), Xl = (_Float16)(-2.f * (float)xl);
  _Float16 Yh = (_Float16)(-2.f * (float)yh), Yl = (_Float16)(-2.f * (float)yl);
  _Float16 Zh = (_Float16)(-2.f * (float)zh), Zl = (_Float16)(-2.f * (float)zl);
  fa = (half8){Xh, Xl, Xh, Xl, Yh, Yl, Yh, Yl};
  fb = (half8){Zh, Zl, Zh, Zl, sh, sl, one, one};
}

__global__ __launch_bounds__(256, 1) void chamfer_full(
    const float* __restrict__ pred, const float* __restrict__ gt,
    float* __restrict__ partial) {
  __shared__ __align__(16) half8 lds[TT * 2];   // 16 KB, A-frag-linear
  __shared__ float wsum[4];
  int bid = blockIdx.x;                // 256 blocks: 2 dir * 4 b * 32 qblk
  int qblk = bid & 31;
  int b    = (bid >> 5) & 3;
  int dir  = bid >> 7;                 // 0: q=pred t=gt ; 1: q=gt t=pred
  const float* qsrc = dir ? gt : pred;
  const float* tsrc = dir ? pred : gt;
  int t = threadIdx.x, lane = t & 63, wave = t >> 6, ql = lane & 31;

  // ---- queries: wave handles 64 queries as two B-frags (layout verified) ----
  const float* qb = qsrc + (size_t)(b * NPTS + qblk * 256 + wave * 64) * 3;
  float q0x = qb[3 * ql],        q0y = qb[3 * ql + 1],        q0z = qb[3 * ql + 2];
  float q1x = qb[3 * (ql + 32)], q1y = qb[3 * (ql + 32) + 1], q1z = qb[3 * (ql + 32) + 2];
  half8 bq0, bq1;
  {
    float s0 = q0x * q0x + q0y * q0y + q0z * q0z;
    float s1 = q1x * q1x + q1y * q1y + q1z * q1z;
    _Float16 x0h, x0l, y0h, y0l, z0h, z0l, s0h, s0l;
    _Float16 x1h, x1l, y1h, y1l, z1h, z1l, s1h, s1l;
    split2(q0x, x0h, x0l); split2(q0y, y0h, y0l); split2(q0z, z0h, z0l); split2(s0, s0h, s0l);
    split2(q1x, x1h, x1l); split2(q1y, y1h, y1l); split2(q1z, z1h, z1l); split2(s1, s1h, s1l);
    _Float16 one = (_Float16)1.0f;
    bq0 = (lane < 32) ? (half8){x0h, x0h, x0l, x0l, y0h, y0h, y0l, y0l}
                      : (half8){z0h, z0h, z0l, z0l, one, one, s0h, s0l};
    bq1 = (lane < 32) ? (half8){x1h, x1h, x1l, x1l, y1h, y1h, y1l, y1l}
                      : (half8){z1h, z1h, z1l, z1l, one, one, s1h, s1l};
  }

  // ---- target loop: 16 chunks, reg-prefetch double-buffer ----
  const float* tb = tsrc + (size_t)b * NPTS * 3;
  // thread t stages points {t, t+256} of each chunk (coalesced 12B/lane)
  float p0x, p0y, p0z, p1x, p1y, p1z;
  {
    const float* s0 = tb + (size_t)t * 3;
    const float* s1 = tb + (size_t)(t + 256) * 3;
    p0x = s0[0]; p0y = s0[1]; p0z = s0[2];
    p1x = s1[0]; p1y = s1[1]; p1z = s1[2];
  }

  float m0 = INFINITY, m1 = INFINITY;
  f32x16 zero = {};
  for (int tc = 0; tc < NCH; ++tc) {
    half8 f0a, f0b, f1a, f1b;
    pack_target(p0x, p0y, p0z, f0a, f0b);
    pack_target(p1x, p1y, p1z, f1a, f1b);
    if (tc) __syncthreads();           // prior chunk's reads done before overwrite
    // A-frag-linear: point k -> lds[(k>>5)*64 + (k&31)] (+32 for frag row 1)
    int base0 = (t >> 5) * 64 + (t & 31);
    lds[base0]            = f0a;
    lds[base0 + 32]       = f0b;
    lds[base0 + 512]      = f1a;       // point t+256 lands 8 tiles later
    lds[base0 + 512 + 32] = f1b;
    // prefetch next chunk while this one computes
    if (tc + 1 < NCH) {
      const float* s0 = tb + (size_t)((tc + 1) * TT + t) * 3;
      const float* s1 = tb + (size_t)((tc + 1) * TT + t + 256) * 3;
      p0x = s0[0]; p0y = s0[1]; p0z = s0[2];
      p1x = s1[0]; p1y = s1[1]; p1z = s1[2];
    }
    __syncthreads();
    #pragma unroll 2
    for (int g = 0; g < TT / 32; ++g) {
      half8 a = lds[g * 64 + lane];    // lane-contiguous: zero bank conflicts
      f32x16 d0 = __builtin_amdgcn_mfma_f32_32x32x16_f16(a, bq0, zero, 0, 0, 0);
      f32x16 d1 = __builtin_amdgcn_mfma_f32_32x32x16_f16(a, bq1, zero, 0, 0, 0);
      m0 = min_fold(m0, d0);
      m1 = min_fold(m1, d1);
    }
  }
  // lane^32 holds the other 16 target rows of each tile
  m0 = fminf(m0, __shfl_xor(m0, 32, 64));
  m1 = fminf(m1, __shfl_xor(m1, 32, 64));

  // ---- block-local sum of 256 final mins -> one plain store ----
  float v = (lane < 32) ? (fmaxf(m0, 0.f) + fmaxf(m1, 0.f)) : 0.f;
  #pragma unroll
  for (int off = 32; off > 0; off >>= 1) v += __shfl_down(v, off, 64);
  if (lane == 0) wsum[wave] = v;
  __syncthreads();
  if (t == 0) partial[bid] = wsum[0] + wsum[1] + wsum[2] + wsum[3];
}

__global__ __launch_bounds__(256) void final_reduce(
    const float* __restrict__ partial, float* __restrict__ out) {
  __shared__ float wsum[4];
  float v = partial[threadIdx.x];
  #pragma unroll
  for (int off = 32; off > 0; off >>= 1) v += __shfl_down(v, off, 64);
  int wave = threadIdx.x >> 6;
  if ((threadIdx.x & 63) == 0) wsum[wave] = v;
  __syncthreads();
  if (threadIdx.x == 0)
    out[0] = (wsum[0] + wsum[1] + wsum[2] + wsum[3]) * (1.0f / 32768.0f);
}

extern "C" void kernel_launch(void* const* d_in, const int* in_sizes, int n_in,
                              void* d_out, int out_size, void* d_ws, size_t ws_size,
                              hipStream_t stream) {
  const float* pred = (const float*)d_in[0];
  const float* gt   = (const float*)d_in[1];
  float* out = (float*)d_out;
  float* partial = (float*)d_ws;      // 256 floats, fully written before read

  chamfer_full<<<256, 256, 0, stream>>>(pred, gt, partial);
  final_reduce<<<1, 256, 0, stream>>>(partial, out);
}

// Round 3
// 76.422 us; speedup vs baseline: 1.3829x; 1.3829x over previous
//
#include <hip/hip_runtime.h>
#include <math.h>

// Chamfer distance via MFMA, pred/gt (4,8192,3) fp32 -> scalar.
// d(q,g) = s_q + s_g - 2 q.g as one K=16 fp16 MFMA dot (2-way fp16 split per
// coord; products exact in fp32 accum):
//   q row:  {xh,xh,xl,xl,yh,yh,yl,yl | zh,zh,zl,zl, 1, 1, sh,sl}
//   t row:  {Xh,Xl,Xh,Xl,Yh,Yl,Yh,Yl | Zh,Zl,Zh,Zl,sh,sl, 1, 1}   (X=-2x etc)
// A = 32 targets, B = 32 queries, v_mfma_f32_32x32x16_f16 (layout verified R5/R6).
// R10: R9 was latency-bound at 1 wave/SIMD (Occ 9.7%, VALUBusy 40%, MfmaUtil
// 11%) -- 256 blocks = 1 block/CU exposed every dep-chain latency. Restore
// TLP: 8-way target split -> 2048 blocks (8/CU = 8 waves/SIMD, LDS 128KB/CU),
// each block = 256 queries x 1024 targets, per-query partial min via plain
// coalesced store into pmin[split][query] (2 MB ws, no atomics). Reduce: 8-way
// min + mean, 64 atomicAdds into out (zero-init by chamfer blk 0, R7 pattern).

typedef _Float16 half8 __attribute__((ext_vector_type(8)));
typedef float f32x16 __attribute__((ext_vector_type(16)));

#define NPTS   8192
#define TT     512                // targets per LDS chunk (16 KB)
#define NSPLIT 8                  // target splits per cloud
#define SCH    2                  // chunks per split (1024 targets)
#define NQ_TOT 65536              // 2 dirs * 32768 queries

__device__ __forceinline__ void split2(float v, _Float16& h, _Float16& l) {
  h = (_Float16)v; l = (_Float16)(v - (float)h);
}

__device__ __forceinline__ float min_fold(float m, const f32x16& d) {
  // v_min3 tree over 16 values + carry-in
  float t0 = fminf(fminf(d[0], d[1]), d[2]);
  float t1 = fminf(fminf(d[3], d[4]), d[5]);
  float t2 = fminf(fminf(d[6], d[7]), d[8]);
  float t3 = fminf(fminf(d[9], d[10]), d[11]);
  float t4 = fminf(fminf(d[12], d[13]), d[14]);
  float t5 = fminf(fminf(t0, t1), d[15]);
  float t6 = fminf(fminf(t2, t3), t4);
  return fminf(m, fminf(t5, t6));
}

__device__ __forceinline__ void pack_target(float x, float y, float z,
                                            half8& fa, half8& fb) {
  float s = x * x + y * y + z * z;
  _Float16 xh, xl, yh, yl, zh, zl, sh, sl;
  split2(x, xh, xl); split2(y, yh, yl); split2(z, zh, zl); split2(s, sh, sl);
  _Float16 one = (_Float16)1.0f;
  _Float16 Xh = (_Float16)(-2.f * (float)xh), Xl = (_Float16)(-2.f * (float)xl);
  _Float16 Yh = (_Float16)(-2.f * (float)yh), Yl = (_Float16)(-2.f * (float)yl);
  _Float16 Zh = (_Float16)(-2.f * (float)zh), Zl = (_Float16)(-2.f * (float)zl);
  fa = (half8){Xh, Xl, Xh, Xl, Yh, Yl, Yh, Yl};
  fb = (half8){Zh, Zl, Zh, Zl, sh, sl, one, one};
}

__global__ __launch_bounds__(256, 8) void chamfer_mfma(
    const float* __restrict__ pred, const float* __restrict__ gt,
    float* __restrict__ pmin, float* __restrict__ out) {
  __shared__ __align__(16) half8 lds[TT * 2];   // 16 KB, A-frag-linear
  int bid = blockIdx.x;            // 2048 = dir(2) * b(4) * qblk(32) * split(8)
  int split = bid & 7;
  int qblk  = (bid >> 3) & 31;
  int b     = (bid >> 8) & 3;
  int dir   = bid >> 10;           // 0: q=pred t=gt ; 1: q=gt t=pred
  const float* qsrc = dir ? gt : pred;
  const float* tsrc = dir ? pred : gt;
  int t = threadIdx.x, lane = t & 63, wave = t >> 6, ql = lane & 31;
  if (bid == 0 && t == 0) out[0] = 0.f;   // reduce runs strictly after

  // ---- queries: wave handles 64 queries as two B-frags (layout verified) ----
  int qstart = qblk * 256 + wave * 64;
  const float* qb = qsrc + (size_t)(b * NPTS + qstart) * 3;
  float q0x = qb[3 * ql],        q0y = qb[3 * ql + 1],        q0z = qb[3 * ql + 2];
  float q1x = qb[3 * (ql + 32)], q1y = qb[3 * (ql + 32) + 1], q1z = qb[3 * (ql + 32) + 2];
  half8 bq0, bq1;
  {
    float s0 = q0x * q0x + q0y * q0y + q0z * q0z;
    float s1 = q1x * q1x + q1y * q1y + q1z * q1z;
    _Float16 x0h, x0l, y0h, y0l, z0h, z0l, s0h, s0l;
    _Float16 x1h, x1l, y1h, y1l, z1h, z1l, s1h, s1l;
    split2(q0x, x0h, x0l); split2(q0y, y0h, y0l); split2(q0z, z0h, z0l); split2(s0, s0h, s0l);
    split2(q1x, x1h, x1l); split2(q1y, y1h, y1l); split2(q1z, z1h, z1l); split2(s1, s1h, s1l);
    _Float16 one = (_Float16)1.0f;
    bq0 = (lane < 32) ? (half8){x0h, x0h, x0l, x0l, y0h, y0h, y0l, y0l}
                      : (half8){z0h, z0h, z0l, z0l, one, one, s0h, s0l};
    bq1 = (lane < 32) ? (half8){x1h, x1h, x1l, x1l, y1h, y1h, y1l, y1l}
                      : (half8){z1h, z1h, z1l, z1l, one, one, s1h, s1l};
  }

  // ---- target loop: SCH chunks of this split, reg-prefetch double-buffer ----
  const float* tb = tsrc + (size_t)(b * NPTS + split * (SCH * TT)) * 3;
  float p0x, p0y, p0z, p1x, p1y, p1z;
  {
    const float* s0 = tb + (size_t)t * 3;
    const float* s1 = tb + (size_t)(t + 256) * 3;
    p0x = s0[0]; p0y = s0[1]; p0z = s0[2];
    p1x = s1[0]; p1y = s1[1]; p1z = s1[2];
  }

  float m0 = INFINITY, m1 = INFINITY;
  f32x16 zero = {};
  for (int tc = 0; tc < SCH; ++tc) {
    half8 f0a, f0b, f1a, f1b;
    pack_target(p0x, p0y, p0z, f0a, f0b);
    pack_target(p1x, p1y, p1z, f1a, f1b);
    if (tc) __syncthreads();           // prior chunk's reads done before overwrite
    // A-frag-linear: point k -> lds[(k>>5)*64 + (k&31)] (+32 for frag row 1)
    int base0 = (t >> 5) * 64 + (t & 31);
    lds[base0]            = f0a;
    lds[base0 + 32]       = f0b;
    lds[base0 + 512]      = f1a;       // point t+256 lands 8 tiles later
    lds[base0 + 512 + 32] = f1b;
    if (tc + 1 < SCH) {                // prefetch next chunk during compute
      const float* s0 = tb + (size_t)((tc + 1) * TT + t) * 3;
      const float* s1 = tb + (size_t)((tc + 1) * TT + t + 256) * 3;
      p0x = s0[0]; p0y = s0[1]; p0z = s0[2];
      p1x = s1[0]; p1y = s1[1]; p1z = s1[2];
    }
    __syncthreads();
    #pragma unroll 2
    for (int g = 0; g < TT / 32; ++g) {
      half8 a = lds[g * 64 + lane];    // lane-contiguous: zero bank conflicts
      f32x16 d0 = __builtin_amdgcn_mfma_f32_32x32x16_f16(a, bq0, zero, 0, 0, 0);
      f32x16 d1 = __builtin_amdgcn_mfma_f32_32x32x16_f16(a, bq1, zero, 0, 0, 0);
      m0 = min_fold(m0, d0);
      m1 = min_fold(m1, d1);
    }
  }
  // lane^32 holds the other 16 target rows of each tile
  m0 = fminf(m0, __shfl_xor(m0, 32, 64));
  m1 = fminf(m1, __shfl_xor(m1, 32, 64));

  // ---- plain coalesced store of this split's partial mins ----
  if (lane < 32) {
    size_t qi = (size_t)dir * 32768 + (size_t)b * NPTS + qstart + ql;
    pmin[(size_t)split * NQ_TOT + qi]      = m0;
    pmin[(size_t)split * NQ_TOT + qi + 32] = m1;
  }
}

__global__ __launch_bounds__(256) void reduce_kernel(
    const float* __restrict__ pmin, float* __restrict__ out) {
  __shared__ float wsum[4];
  float acc = 0.f;
  for (int i = blockIdx.x * 256 + threadIdx.x; i < NQ_TOT; i += 64 * 256) {
    float v = pmin[i];
    #pragma unroll
    for (int s = 1; s < NSPLIT; ++s) v = fminf(v, pmin[(size_t)s * NQ_TOT + i]);
    acc += fmaxf(v, 0.f);
  }
  acc *= (1.0f / 32768.0f);
  #pragma unroll
  for (int off = 32; off > 0; off >>= 1) acc += __shfl_down(acc, off, 64);
  int wid = threadIdx.x >> 6;
  if ((threadIdx.x & 63) == 0) wsum[wid] = acc;
  __syncthreads();
  if (threadIdx.x == 0) atomicAdd(out, wsum[0] + wsum[1] + wsum[2] + wsum[3]);
}

extern "C" void kernel_launch(void* const* d_in, const int* in_sizes, int n_in,
                              void* d_out, int out_size, void* d_ws, size_t ws_size,
                              hipStream_t stream) {
  const float* pred = (const float*)d_in[0];
  const float* gt   = (const float*)d_in[1];
  float* out = (float*)d_out;
  float* pmin = (float*)d_ws;         // 8 * 65536 * 4 B = 2 MB partial mins

  chamfer_mfma<<<2048, 256, 0, stream>>>(pred, gt, pmin, out);
  reduce_kernel<<<64, 256, 0, stream>>>(pmin, out);
}

// Round 4
// 73.875 us; speedup vs baseline: 1.4306x; 1.0345x over previous
//
#include <hip/hip_runtime.h>
#include <math.h>

// Chamfer distance via MFMA, pred/gt (4,8192,3) fp32 -> scalar.
// d(q,g) = s_q + s_g - 2 q.g as one K=16 fp16 MFMA dot (2-way fp16 split per
// coord; products exact in fp32 accum):
//   q row:  {xh,xh,xl,xl,yh,yh,yl,yl | zh,zh,zl,zl, 1, 1, sh,sl}
//   t row:  {Xh,Xl,Xh,Xl,Yh,Yl,Yh,Yl | Zh,Zl,Zh,Zl,sh,sl, 1, 1}   (X=-2x etc)
// A = 32 targets, B = 32 queries, v_mfma_f32_32x32x16_f16 (layout verified R5/R6).
// R11: chamfer inferred ~26us vs 6.9us MFMA floor. Two causes attacked:
// (1) per-MFMA depth-4 serial min-tree -> replaced by depth-1 v_min3
//     accumulate into persistent vacc[8] (all 16 C-regs of a lane = ONE query,
//     col=lane&31), tree-fold once per wave at the end;
// (2) launch_bounds(256,8)'s 64-VGPR cap (possible AGPR shuffling / forced
//     serialization) -> (256,4) = 128-VGPR budget, NSPLIT=4: 1024 blocks =
//     4 blocks/CU, 4 chunks each (startup amortized 2x), LDS 68KB/CU.

typedef _Float16 half8 __attribute__((ext_vector_type(8)));
typedef float f32x16 __attribute__((ext_vector_type(16)));

#define NPTS   8192
#define TT     512                // targets per LDS chunk (16 KB)
#define NSPLIT 4                  // target splits per cloud
#define SCH    4                  // chunks per split (2048 targets)
#define NQ_TOT 65536              // 2 dirs * 32768 queries

__device__ __forceinline__ void split2(float v, _Float16& h, _Float16& l) {
  h = (_Float16)v; l = (_Float16)(v - (float)h);
}

__device__ __forceinline__ void pack_target(float x, float y, float z,
                                            half8& fa, half8& fb) {
  float s = x * x + y * y + z * z;
  _Float16 xh, xl, yh, yl, zh, zl, sh, sl;
  split2(x, xh, xl); split2(y, yh, yl); split2(z, zh, zl); split2(s, sh, sl);
  _Float16 one = (_Float16)1.0f;
  _Float16 Xh = (_Float16)(-2.f * (float)xh), Xl = (_Float16)(-2.f * (float)xl);
  _Float16 Yh = (_Float16)(-2.f * (float)yh), Yl = (_Float16)(-2.f * (float)yl);
  _Float16 Zh = (_Float16)(-2.f * (float)zh), Zl = (_Float16)(-2.f * (float)zl);
  fa = (half8){Xh, Xl, Xh, Xl, Yh, Yl, Yh, Yl};
  fb = (half8){Zh, Zl, Zh, Zl, sh, sl, one, one};
}

__global__ __launch_bounds__(256, 4) void chamfer_mfma(
    const float* __restrict__ pred, const float* __restrict__ gt,
    float* __restrict__ pmin, float* __restrict__ out) {
  __shared__ __align__(16) half8 lds[TT * 2];   // 16 KB, A-frag-linear
  int bid = blockIdx.x;            // 1024 = dir(2) * b(4) * qblk(32) * split(4)
  int split = bid & 3;
  int qblk  = (bid >> 2) & 31;
  int b     = (bid >> 7) & 3;
  int dir   = bid >> 9;            // 0: q=pred t=gt ; 1: q=gt t=pred
  const float* qsrc = dir ? gt : pred;
  const float* tsrc = dir ? pred : gt;
  int t = threadIdx.x, lane = t & 63, wave = t >> 6, ql = lane & 31;
  if (bid == 0 && t == 0) out[0] = 0.f;   // reduce runs strictly after

  // ---- queries: wave handles 64 queries as two B-frags (layout verified) ----
  int qstart = qblk * 256 + wave * 64;
  const float* qb = qsrc + (size_t)(b * NPTS + qstart) * 3;
  float q0x = qb[3 * ql],        q0y = qb[3 * ql + 1],        q0z = qb[3 * ql + 2];
  float q1x = qb[3 * (ql + 32)], q1y = qb[3 * (ql + 32) + 1], q1z = qb[3 * (ql + 32) + 2];
  half8 bq0, bq1;
  {
    float s0 = q0x * q0x + q0y * q0y + q0z * q0z;
    float s1 = q1x * q1x + q1y * q1y + q1z * q1z;
    _Float16 x0h, x0l, y0h, y0l, z0h, z0l, s0h, s0l;
    _Float16 x1h, x1l, y1h, y1l, z1h, z1l, s1h, s1l;
    split2(q0x, x0h, x0l); split2(q0y, y0h, y0l); split2(q0z, z0h, z0l); split2(s0, s0h, s0l);
    split2(q1x, x1h, x1l); split2(q1y, y1h, y1l); split2(q1z, z1h, z1l); split2(s1, s1h, s1l);
    _Float16 one = (_Float16)1.0f;
    bq0 = (lane < 32) ? (half8){x0h, x0h, x0l, x0l, y0h, y0h, y0l, y0l}
                      : (half8){z0h, z0h, z0l, z0l, one, one, s0h, s0l};
    bq1 = (lane < 32) ? (half8){x1h, x1h, x1l, x1l, y1h, y1h, y1l, y1l}
                      : (half8){z1h, z1h, z1l, z1l, one, one, s1h, s1l};
  }

  // ---- target loop: SCH chunks of this split, reg-prefetch double-buffer ----
  const float* tb = tsrc + (size_t)(b * NPTS + split * (SCH * TT)) * 3;
  float p0x, p0y, p0z, p1x, p1y, p1z;
  {
    const float* s0 = tb + (size_t)t * 3;
    const float* s1 = tb + (size_t)(t + 256) * 3;
    p0x = s0[0]; p0y = s0[1]; p0z = s0[2];
    p1x = s1[0]; p1y = s1[1]; p1z = s1[2];
  }

  // persistent vector-min accumulators: depth-1 folds, no serial chain
  float vacc0[8], vacc1[8];
  #pragma unroll
  for (int j = 0; j < 8; ++j) { vacc0[j] = INFINITY; vacc1[j] = INFINITY; }

  f32x16 zero = {};
  for (int tc = 0; tc < SCH; ++tc) {
    half8 f0a, f0b, f1a, f1b;
    pack_target(p0x, p0y, p0z, f0a, f0b);
    pack_target(p1x, p1y, p1z, f1a, f1b);
    if (tc) __syncthreads();           // prior chunk's reads done before overwrite
    // A-frag-linear: point k -> lds[(k>>5)*64 + (k&31)] (+32 for frag row 1)
    int base0 = (t >> 5) * 64 + (t & 31);
    lds[base0]            = f0a;
    lds[base0 + 32]       = f0b;
    lds[base0 + 512]      = f1a;       // point t+256 lands 8 tiles later
    lds[base0 + 512 + 32] = f1b;
    if (tc + 1 < SCH) {                // prefetch next chunk during compute
      const float* s0 = tb + (size_t)((tc + 1) * TT + t) * 3;
      const float* s1 = tb + (size_t)((tc + 1) * TT + t + 256) * 3;
      p0x = s0[0]; p0y = s0[1]; p0z = s0[2];
      p1x = s1[0]; p1y = s1[1]; p1z = s1[2];
    }
    __syncthreads();
    #pragma unroll 2
    for (int g = 0; g < TT / 32; ++g) {
      half8 a = lds[g * 64 + lane];    // lane-contiguous: zero bank conflicts
      f32x16 d0 = __builtin_amdgcn_mfma_f32_32x32x16_f16(a, bq0, zero, 0, 0, 0);
      f32x16 d1 = __builtin_amdgcn_mfma_f32_32x32x16_f16(a, bq1, zero, 0, 0, 0);
      #pragma unroll
      for (int j = 0; j < 8; ++j) {    // 16 independent v_min3, depth 1
        vacc0[j] = fminf(fminf(vacc0[j], d0[2 * j]), d0[2 * j + 1]);
        vacc1[j] = fminf(fminf(vacc1[j], d1[2 * j]), d1[2 * j + 1]);
      }
    }
  }
  // end-of-wave tree fold (once, amortized over 128 MFMAs)
  float a0 = fminf(fminf(vacc0[0], vacc0[1]), vacc0[2]);
  float a1 = fminf(fminf(vacc0[3], vacc0[4]), vacc0[5]);
  float a2 = fminf(vacc0[6], vacc0[7]);
  float m0 = fminf(fminf(a0, a1), a2);
  float b0 = fminf(fminf(vacc1[0], vacc1[1]), vacc1[2]);
  float b1 = fminf(fminf(vacc1[3], vacc1[4]), vacc1[5]);
  float b2 = fminf(vacc1[6], vacc1[7]);
  float m1 = fminf(fminf(b0, b1), b2);
  // lane^32 holds the other 16 target rows of each tile
  m0 = fminf(m0, __shfl_xor(m0, 32, 64));
  m1 = fminf(m1, __shfl_xor(m1, 32, 64));

  // ---- plain coalesced store of this split's partial mins ----
  if (lane < 32) {
    size_t qi = (size_t)dir * 32768 + (size_t)b * NPTS + qstart + ql;
    pmin[(size_t)split * NQ_TOT + qi]      = m0;
    pmin[(size_t)split * NQ_TOT + qi + 32] = m1;
  }
}

__global__ __launch_bounds__(256) void reduce_kernel(
    const float* __restrict__ pmin, float* __restrict__ out) {
  __shared__ float wsum[4];
  float acc = 0.f;
  for (int i = blockIdx.x * 256 + threadIdx.x; i < NQ_TOT; i += 64 * 256) {
    float v = pmin[i];
    #pragma unroll
    for (int s = 1; s < NSPLIT; ++s) v = fminf(v, pmin[(size_t)s * NQ_TOT + i]);
    acc += fmaxf(v, 0.f);
  }
  acc *= (1.0f / 32768.0f);
  #pragma unroll
  for (int off = 32; off > 0; off >>= 1) acc += __shfl_down(acc, off, 64);
  int wid = threadIdx.x >> 6;
  if ((threadIdx.x & 63) == 0) wsum[wid] = acc;
  __syncthreads();
  if (threadIdx.x == 0) atomicAdd(out, wsum[0] + wsum[1] + wsum[2] + wsum[3]);
}

extern "C" void kernel_launch(void* const* d_in, const int* in_sizes, int n_in,
                              void* d_out, int out_size, void* d_ws, size_t ws_size,
                              hipStream_t stream) {
  const float* pred = (const float*)d_in[0];
  const float* gt   = (const float*)d_in[1];
  float* out = (float*)d_out;
  float* pmin = (float*)d_ws;         // 4 * 65536 * 4 B = 1 MB partial mins

  chamfer_mfma<<<1024, 256, 0, stream>>>(pred, gt, pmin, out);
  reduce_kernel<<<64, 256, 0, stream>>>(pmin, out);
}

// Round 5
// 73.188 us; speedup vs baseline: 1.4440x; 1.0094x over previous
//
#include <hip/hip_runtime.h>
#include <math.h>

// Chamfer distance via MFMA, pred/gt (4,8192,3) fp32 -> scalar.
// d(q,g) = s_q + s_g - 2 q.g as one K=16 fp16 MFMA dot (2-way fp16 split per
// coord; products exact in fp32 accum):
//   q row:  {xh,xh,xl,xl,yh,yh,yl,yl | zh,zh,zl,zl, 1, 1, sh,sl}
//   t row:  {Xh,Xl,Xh,Xl,Yh,Yl,Yh,Yl | Zh,Zl,Zh,Zl,sh,sl, 1, 1}   (X=-2x etc)
// A = 32 targets, B = 32 queries, v_mfma_f32_32x32x16_f16 (layout verified R5/R6).
// R12: R9's VGPR_Count=36 proves MFMA C/D lived in AGPRs -> fold paid ~32
// v_accvgpr_read per g-iter (R9 VALUBusy 40% at 1 wave/SIMD => ~70 VALU
// instr/g-iter vs ~20 modeled). Fixes:
//  (1) empty inline-asm "+v" pins each f32x16 MFMA result to ArchVGPRs
//      (v_mfma writes v[] directly on gfx950 unified file -> zero moves,
//      min-fold fuses to v_min3_f32 on VGPR operands);
//  (2) fold runs one g-iter BEHIND the MFMAs (software pipeline) so MFMA
//      result latency is off the critical path.
// Grid: NSPLIT=4, 1024 blocks = 4 blocks/CU, LDS 68KB/CU, ~110 VGPR -> (256,4).

typedef _Float16 half8 __attribute__((ext_vector_type(8)));
typedef float f32x16 __attribute__((ext_vector_type(16)));

#define NPTS   8192
#define TT     512                // targets per LDS chunk (16 KB)
#define NSPLIT 4                  // target splits per cloud
#define SCH    4                  // chunks per split (2048 targets)
#define NQ_TOT 65536              // 2 dirs * 32768 queries

__device__ __forceinline__ void split2(float v, _Float16& h, _Float16& l) {
  h = (_Float16)v; l = (_Float16)(v - (float)h);
}

__device__ __forceinline__ void pack_target(float x, float y, float z,
                                            half8& fa, half8& fb) {
  float s = x * x + y * y + z * z;
  _Float16 xh, xl, yh, yl, zh, zl, sh, sl;
  split2(x, xh, xl); split2(y, yh, yl); split2(z, zh, zl); split2(s, sh, sl);
  _Float16 one = (_Float16)1.0f;
  _Float16 Xh = (_Float16)(-2.f * (float)xh), Xl = (_Float16)(-2.f * (float)xl);
  _Float16 Yh = (_Float16)(-2.f * (float)yh), Yl = (_Float16)(-2.f * (float)yl);
  _Float16 Zh = (_Float16)(-2.f * (float)zh), Zl = (_Float16)(-2.f * (float)zl);
  fa = (half8){Xh, Xl, Xh, Xl, Yh, Yl, Yh, Yl};
  fb = (half8){Zh, Zl, Zh, Zl, sh, sl, one, one};
}

__global__ __launch_bounds__(256, 4) void chamfer_mfma(
    const float* __restrict__ pred, const float* __restrict__ gt,
    float* __restrict__ pmin, float* __restrict__ out) {
  __shared__ __align__(16) half8 lds[TT * 2];   // 16 KB, A-frag-linear
  int bid = blockIdx.x;            // 1024 = dir(2) * b(4) * qblk(32) * split(4)
  int split = bid & 3;
  int qblk  = (bid >> 2) & 31;
  int b     = (bid >> 7) & 3;
  int dir   = bid >> 9;            // 0: q=pred t=gt ; 1: q=gt t=pred
  const float* qsrc = dir ? gt : pred;
  const float* tsrc = dir ? pred : gt;
  int t = threadIdx.x, lane = t & 63, wave = t >> 6, ql = lane & 31;
  if (bid == 0 && t == 0) out[0] = 0.f;   // reduce runs strictly after

  // ---- queries: wave handles 64 queries as two B-frags (layout verified) ----
  int qstart = qblk * 256 + wave * 64;
  const float* qb = qsrc + (size_t)(b * NPTS + qstart) * 3;
  float q0x = qb[3 * ql],        q0y = qb[3 * ql + 1],        q0z = qb[3 * ql + 2];
  float q1x = qb[3 * (ql + 32)], q1y = qb[3 * (ql + 32) + 1], q1z = qb[3 * (ql + 32) + 2];
  half8 bq0, bq1;
  {
    float s0 = q0x * q0x + q0y * q0y + q0z * q0z;
    float s1 = q1x * q1x + q1y * q1y + q1z * q1z;
    _Float16 x0h, x0l, y0h, y0l, z0h, z0l, s0h, s0l;
    _Float16 x1h, x1l, y1h, y1l, z1h, z1l, s1h, s1l;
    split2(q0x, x0h, x0l); split2(q0y, y0h, y0l); split2(q0z, z0h, z0l); split2(s0, s0h, s0l);
    split2(q1x, x1h, x1l); split2(q1y, y1h, y1l); split2(q1z, z1h, z1l); split2(s1, s1h, s1l);
    _Float16 one = (_Float16)1.0f;
    bq0 = (lane < 32) ? (half8){x0h, x0h, x0l, x0l, y0h, y0h, y0l, y0l}
                      : (half8){z0h, z0h, z0l, z0l, one, one, s0h, s0l};
    bq1 = (lane < 32) ? (half8){x1h, x1h, x1l, x1l, y1h, y1h, y1l, y1l}
                      : (half8){z1h, z1h, z1l, z1l, one, one, s1h, s1l};
  }

  // ---- target loop: SCH chunks of this split, reg-prefetch double-buffer ----
  const float* tb = tsrc + (size_t)(b * NPTS + split * (SCH * TT)) * 3;
  float p0x, p0y, p0z, p1x, p1y, p1z;
  {
    const float* s0 = tb + (size_t)t * 3;
    const float* s1 = tb + (size_t)(t + 256) * 3;
    p0x = s0[0]; p0y = s0[1]; p0z = s0[2];
    p1x = s1[0]; p1y = s1[1]; p1z = s1[2];
  }

  // persistent vector-min accumulators: depth-1 v_min3 folds
  float vacc0[8], vacc1[8];
  #pragma unroll
  for (int j = 0; j < 8; ++j) { vacc0[j] = INFINITY; vacc1[j] = INFINITY; }

  f32x16 zero = {};
  for (int tc = 0; tc < SCH; ++tc) {
    half8 f0a, f0b, f1a, f1b;
    pack_target(p0x, p0y, p0z, f0a, f0b);
    pack_target(p1x, p1y, p1z, f1a, f1b);
    if (tc) __syncthreads();           // prior chunk's reads done before overwrite
    // A-frag-linear: point k -> lds[(k>>5)*64 + (k&31)] (+32 for frag row 1)
    int base0 = (t >> 5) * 64 + (t & 31);
    lds[base0]            = f0a;
    lds[base0 + 32]       = f0b;
    lds[base0 + 512]      = f1a;       // point t+256 lands 8 tiles later
    lds[base0 + 512 + 32] = f1b;
    if (tc + 1 < SCH) {                // prefetch next chunk during compute
      const float* s0 = tb + (size_t)((tc + 1) * TT + t) * 3;
      const float* s1 = tb + (size_t)((tc + 1) * TT + t + 256) * 3;
      p0x = s0[0]; p0y = s0[1]; p0z = s0[2];
      p1x = s1[0]; p1y = s1[1]; p1z = s1[2];
    }
    __syncthreads();

    // ---- software-pipelined inner loop: fold runs one g-iter behind ----
    half8 a0 = lds[lane];
    f32x16 d0 = __builtin_amdgcn_mfma_f32_32x32x16_f16(a0, bq0, zero, 0, 0, 0);
    f32x16 d1 = __builtin_amdgcn_mfma_f32_32x32x16_f16(a0, bq1, zero, 0, 0, 0);
    asm("" : "+v"(d0), "+v"(d1));      // pin results to ArchVGPRs (no AGPR moves)
    #pragma unroll
    for (int g = 1; g < TT / 32; ++g) {
      half8 a = lds[g * 64 + lane];    // lane-contiguous: zero bank conflicts
      f32x16 e0 = __builtin_amdgcn_mfma_f32_32x32x16_f16(a, bq0, zero, 0, 0, 0);
      f32x16 e1 = __builtin_amdgcn_mfma_f32_32x32x16_f16(a, bq1, zero, 0, 0, 0);
      asm("" : "+v"(e0), "+v"(e1));
      #pragma unroll
      for (int j = 0; j < 8; ++j) {    // fold PREVIOUS tile: 16 v_min3, depth 1
        vacc0[j] = fminf(fminf(vacc0[j], d0[2 * j]), d0[2 * j + 1]);
        vacc1[j] = fminf(fminf(vacc1[j], d1[2 * j]), d1[2 * j + 1]);
      }
      d0 = e0; d1 = e1;
    }
    #pragma unroll
    for (int j = 0; j < 8; ++j) {      // epilogue: fold the last tile
      vacc0[j] = fminf(fminf(vacc0[j], d0[2 * j]), d0[2 * j + 1]);
      vacc1[j] = fminf(fminf(vacc1[j], d1[2 * j]), d1[2 * j + 1]);
    }
  }
  // end-of-wave tree fold (once, amortized over 128 MFMAs)
  float a0 = fminf(fminf(vacc0[0], vacc0[1]), vacc0[2]);
  float a1 = fminf(fminf(vacc0[3], vacc0[4]), vacc0[5]);
  float a2 = fminf(vacc0[6], vacc0[7]);
  float m0 = fminf(fminf(a0, a1), a2);
  float b0 = fminf(fminf(vacc1[0], vacc1[1]), vacc1[2]);
  float b1 = fminf(fminf(vacc1[3], vacc1[4]), vacc1[5]);
  float b2 = fminf(vacc1[6], vacc1[7]);
  float m1 = fminf(fminf(b0, b1), b2);
  // lane^32 holds the other 16 target rows of each tile
  m0 = fminf(m0, __shfl_xor(m0, 32, 64));
  m1 = fminf(m1, __shfl_xor(m1, 32, 64));

  // ---- plain coalesced store of this split's partial mins ----
  if (lane < 32) {
    size_t qi = (size_t)dir * 32768 + (size_t)b * NPTS + qstart + ql;
    pmin[(size_t)split * NQ_TOT + qi]      = m0;
    pmin[(size_t)split * NQ_TOT + qi + 32] = m1;
  }
}

__global__ __launch_bounds__(256) void reduce_kernel(
    const float* __restrict__ pmin, float* __restrict__ out) {
  __shared__ float wsum[4];
  float acc = 0.f;
  for (int i = blockIdx.x * 256 + threadIdx.x; i < NQ_TOT; i += 64 * 256) {
    float v = pmin[i];
    #pragma unroll
    for (int s = 1; s < NSPLIT; ++s) v = fminf(v, pmin[(size_t)s * NQ_TOT + i]);
    acc += fmaxf(v, 0.f);
  }
  acc *= (1.0f / 32768.0f);
  #pragma unroll
  for (int off = 32; off > 0; off >>= 1) acc += __shfl_down(acc, off, 64);
  int wid = threadIdx.x >> 6;
  if ((threadIdx.x & 63) == 0) wsum[wid] = acc;
  __syncthreads();
  if (threadIdx.x == 0) atomicAdd(out, wsum[0] + wsum[1] + wsum[2] + wsum[3]);
}

extern "C" void kernel_launch(void* const* d_in, const int* in_sizes, int n_in,
                              void* d_out, int out_size, void* d_ws, size_t ws_size,
                              hipStream_t stream) {
  const float* pred = (const float*)d_in[0];
  const float* gt   = (const float*)d_in[1];
  float* out = (float*)d_out;
  float* pmin = (float*)d_ws;         // 4 * 65536 * 4 B = 1 MB partial mins

  chamfer_mfma<<<1024, 256, 0, stream>>>(pred, gt, pmin, out);
  reduce_kernel<<<64, 256, 0, stream>>>(pmin, out);
}